// Round 5
// baseline (184.011 us; speedup 1.0000x reference)
//
#include <hip/hip_runtime.h>
#include <hip/hip_bf16.h>
#include <stdint.h>

// Correlation (FlowNet), md=4: out[b, di*9+dj, h, w] = sum_c x[b,c,h,w]*yp[b,c,h+di-4,w+dj-4] / 256
// R4: occupancy + independence. 256-thr blocks (4 waves): wave = (hh = h-row h0+hh,
// dh = di-half {0..4}/{4..8}); acc 40 regs; x loaded global-direct (no x LDS);
// y-only LDS 10 rows x 1KB, double-buffered (20 KB). di=4 double-computed by both
// dh-waves -> bitwise-identical benign double-write, keeps code uniform.

using f32x4 = __attribute__((ext_vector_type(4))) float;
using s16x4 = __attribute__((ext_vector_type(4))) short;
using u16x4 = __attribute__((ext_vector_type(4))) unsigned short;

#define C_DIM 256
#define H_DIM 96
#define W_DIM 192
#define HWSZ  (H_DIM * W_DIM)
#define MD 4
#define KD 9
#define CHUNK 16
#define NCHUNK 16
#define NTHR 256
#define WTILES 12                // 192/16
#define HQ 48                    // 96/2
#define SUB_B 128                // [4c][16s] bf16 subtile, 128B-aligned (tr native)
#define YROW_B (8 * SUB_B)       // 1024 B per y row (2 t-tiles x 4 cg)
#define NROWS 10                 // y rows h0-4 .. h0+5
#define BUFSZ (NROWS * YROW_B)   // 10240
#define LDS_BYTES (2 * BUFSZ)    // 20480
#define NYQ (NROWS * CHUNK * 6)  // 960 staged 16B-quads per chunk

static __device__ __forceinline__ unsigned short bf16b(float f) {
  __bf16 h = (__bf16)f;                   // RNE
  unsigned short s; __builtin_memcpy(&s, &h, 2); return s;
}

static __device__ __forceinline__ s16x4 tr16(uint32_t addr) {
  s16x4 d;
  asm volatile("ds_read_b64_tr_b16 %0, %1" : "=v"(d) : "v"(addr));
  return d;
}

#define WAITLG(n) asm volatile("s_waitcnt lgkmcnt(" #n ")" ::: "memory")

__global__ __launch_bounds__(NTHR, 4)
void corr_mfma(const float* __restrict__ xg, const float* __restrict__ yg,
               float* __restrict__ outg) {
  __shared__ __align__(16) char smem[LDS_BYTES];

  const int bid = blockIdx.x;             // 4608 = 8 * 48 * 12
  const int b   = bid & 7;                // batch == XCD round-robin
  const int rem = bid >> 3;               // hq fastest -> h-halo L2 reuse
  const int wt  = rem / HQ;
  const int hq  = rem - wt * HQ;
  const int w0  = wt * 16;
  const int h0  = hq * 2;

  const int tid  = threadIdx.x;
  const int lane = tid & 63;
  const int wv   = tid >> 6;              // 0..3
  const int hh   = wv & 1;                // h-row h0+hh
  const int dh   = wv >> 1;               // di half: dh*4 + dl, dl 0..4
  const int hi   = lane >> 4;
  const int lm   = lane & 15;

  const uint32_t sbase = (uint32_t)(uintptr_t)&smem[0];

  // ---- y staging decode, hoisted: 960 quads, up to 4 per thread (slot 3 partial)
  uint32_t goffY[4], loffY[4];
  uint32_t vmY = 0;                       // bit i: do load (in-bounds); exists & OOB -> zero-fill
  uint32_t exY = 0;                       // bit i: slot exists (write LDS)
#pragma unroll
  for (int i = 0; i < 4; ++i) {
    const int qid = i * NTHR + tid;
    if (qid < NYQ) {
      exY |= (1u << i);
      const int q = qid % 6;
      const int c = (qid / 6) & 15;
      const int r = qid / 96;             // 0..9 -> y row h0+r-4
      const int hg = h0 + r - MD;
      const int sg = w0 - MD + 4 * q;     // 4-aligned: OOB is whole-quad
      const bool ok = (hg >= 0) && (hg < H_DIM) && (sg >= 0) && (sg < W_DIM);
      if (ok) vmY |= (1u << i);
      goffY[i] = ok ? (uint32_t)(((b * C_DIM + c) * H_DIM + hg) * W_DIM + sg) : 0u;
      const int s = 4 * q;
      loffY[i] = r * YROW_B + (s >> 4) * 512 + (c >> 2) * SUB_B + (c & 3) * 32 + (s & 15) * 2;
    } else {
      goffY[i] = 0u; loffY[i] = 0u;
    }
  }

  // ---- x global-direct A-frag addresses: lane (hi,lm) reads c = c0+hi*4+e at (h, w0+lm)
  const int h = h0 + hh;
  uint32_t xoff[4];
#pragma unroll
  for (int e = 0; e < 4; ++e)
    xoff[e] = (uint32_t)(((b * C_DIM + hi * 4 + e) * H_DIM + h) * W_DIM + w0 + lm);

  f32x4 acc[5][2];
#pragma unroll
  for (int dl = 0; dl < 5; ++dl) {
    acc[dl][0] = f32x4{0.f, 0.f, 0.f, 0.f};
    acc[dl][1] = f32x4{0.f, 0.f, 0.f, 0.f};
  }

  // B tr base: y LDS row for (dh, dl) is hh + dh*4 + dl
  const uint32_t bbase = sbase + (uint32_t)(hh + dh * 4) * YROW_B + hi * SUB_B + lm * 8;

  // ---- prologue: stage chunk 0 into buf0
  {
    float4 v[4];
#pragma unroll
    for (int i = 0; i < 4; ++i) {
      float4 t4 = make_float4(0.f, 0.f, 0.f, 0.f);
      if (vmY & (1u << i)) t4 = *(const float4*)(yg + goffY[i]);
      v[i] = t4;
    }
#pragma unroll
    for (int i = 0; i < 4; ++i)
      if (exY & (1u << i))
        *(u16x4*)(smem + loffY[i]) =
            u16x4{bf16b(v[i].x), bf16b(v[i].y), bf16b(v[i].z), bf16b(v[i].w)};
  }
  __syncthreads();

  for (int t = 0; t < NCHUNK; ++t) {
    const uint32_t co = (uint32_t)t * CHUNK * HWSZ;

    // ---- A frag: 4 global dwords + cvt (compiler inserts vmcnt before cvt)
    float xa0 = xg[xoff[0] + co], xa1 = xg[xoff[1] + co];
    float xa2 = xg[xoff[2] + co], xa3 = xg[xoff[3] + co];
    s16x4 afr;
    afr[0] = (short)bf16b(xa0); afr[1] = (short)bf16b(xa1);
    afr[2] = (short)bf16b(xa2); afr[3] = (short)bf16b(xa3);

    // ---- issue next chunk's y loads (latency hides under compute below)
    float4 v[4];
    if (t + 1 < NCHUNK) {
      const uint32_t cn = co + CHUNK * HWSZ;
#pragma unroll
      for (int i = 0; i < 4; ++i) {
        float4 t4 = make_float4(0.f, 0.f, 0.f, 0.f);
        if (vmY & (1u << i)) t4 = *(const float4*)(yg + goffY[i] + cn);
        v[i] = t4;
      }
    }

    // ---- B frags: issue all 10 tr reads, then counted waits + MFMA
    const uint32_t bo = (uint32_t)(t & 1) * BUFSZ;
    s16x4 bf[5][2];
#pragma unroll
    for (int dl = 0; dl < 5; ++dl) {
      bf[dl][0] = tr16(bbase + bo + (uint32_t)dl * YROW_B);
      bf[dl][1] = tr16(bbase + bo + (uint32_t)dl * YROW_B + 512);
    }

#define DO_DI(dl, lg) \
    WAITLG(lg); __builtin_amdgcn_sched_barrier(0); \
    acc[dl][0] = __builtin_amdgcn_mfma_f32_16x16x16bf16_1k(afr, bf[dl][0], acc[dl][0], 0, 0, 0); \
    acc[dl][1] = __builtin_amdgcn_mfma_f32_16x16x16bf16_1k(afr, bf[dl][1], acc[dl][1], 0, 0, 0);

    __builtin_amdgcn_s_setprio(1);
    DO_DI(0, 8)
    DO_DI(1, 6)
    DO_DI(2, 4)
    DO_DI(3, 2)
    DO_DI(4, 0)
    __builtin_amdgcn_s_setprio(0);
#undef DO_DI

    // ---- convert + store next chunk to buf[(t+1)&1]
    if (t + 1 < NCHUNK) {
      const uint32_t wo = (uint32_t)((t + 1) & 1) * BUFSZ;
#pragma unroll
      for (int i = 0; i < 4; ++i)
        if (exY & (1u << i))
          *(u16x4*)(smem + wo + loffY[i]) =
              u16x4{bf16b(v[i].x), bf16b(v[i].y), bf16b(v[i].z), bf16b(v[i].w)};
    }
    // single barrier per chunk: write targets the buffer last read in compute(t-1);
    // this chunk's reads are drained by WAITLG(0) above.
    __syncthreads();
  }

  // ---- epilogue: D[m][n]: n=lm, m=hi*4+rg. dj = tt*16 + lm - m. di = dh*4+dl.
  // di=4 written by both dh-waves with bitwise-identical values (benign).
  const float scale = 1.f / 256.f;
#pragma unroll
  for (int dl = 0; dl < 5; ++dl) {
    const int di = dh * 4 + dl;
#pragma unroll
    for (int tt = 0; tt < 2; ++tt) {
#pragma unroll
      for (int rg = 0; rg < 4; ++rg) {
        const int m = hi * 4 + rg;
        const int dj = tt * 16 + lm - m;
        if (0 <= dj && dj <= 8) {
          outg[((b * (KD * KD) + di * KD + dj) * H_DIM + h) * W_DIM + w0 + m] =
              acc[dl][tt][rg] * scale;
        }
      }
    }
  }
}

extern "C" void kernel_launch(void* const* d_in, const int* in_sizes, int n_in,
                              void* d_out, int out_size, void* d_ws, size_t ws_size,
                              hipStream_t stream) {
  const float* x = (const float*)d_in[0];
  const float* y = (const float*)d_in[1];
  float* out = (float*)d_out;
  (void)in_sizes; (void)n_in; (void)d_ws; (void)ws_size; (void)out_size;

  const int grid = 8 * HQ * WTILES;       // 4608 blocks, 256 threads
  corr_mfma<<<dim3(grid), dim3(NTHR), 0, stream>>>(x, y, out);
}

// Round 6
// 153.404 us; speedup vs baseline: 1.1995x; 1.1995x over previous
//
#include <hip/hip_runtime.h>
#include <hip/hip_bf16.h>
#include <stdint.h>

// Correlation (FlowNet), md=4: out[b, di*9+dj, h, w] = sum_c x[b,c,h,w]*yp[b,c,h+di-4,w+dj-4] / 256
// R5: CHUNK=32 long phases (8 chunks) + di-split waves (acc 40) + 2-deep load
// prefetch (loads issued one full iteration ahead) + x global-direct + 128B subtiles.
// Block: 512 thr = 8 waves = (hh 0..3) x (dh 0..1); HR=4 output rows; y rows h0-4..h0+7.

using f32x4 = __attribute__((ext_vector_type(4))) float;
using s16x4 = __attribute__((ext_vector_type(4))) short;
using u16x4 = __attribute__((ext_vector_type(4))) unsigned short;

#define C_DIM 256
#define H_DIM 96
#define W_DIM 192
#define HWSZ  (H_DIM * W_DIM)
#define MD 4
#define KD 9
#define CHUNK 32
#define NCHUNK 8
#define NTHR 512
#define WTILES 12                // 192/16
#define HQ 24                    // 96/4
#define SUB_B 128                // [4c][16s] bf16 subtile, 128B-aligned (tr native)
#define YROW_B (16 * SUB_B)      // 2 t-tiles x 8 cg x 128B = 2048 B per y row (32c)
#define NROWS 12                 // y rows h0-4 .. h0+7
#define BUFSZ (NROWS * YROW_B)   // 24576
#define LDS_BYTES (2 * BUFSZ)    // 49152
#define NYQ (NROWS * CHUNK * 6)  // 2304 staged 16B-quads per chunk

static __device__ __forceinline__ unsigned short bf16b(float f) {
  __bf16 h = (__bf16)f;                   // RNE
  unsigned short s; __builtin_memcpy(&s, &h, 2); return s;
}

static __device__ __forceinline__ s16x4 tr16(uint32_t addr) {
  s16x4 d;
  asm volatile("ds_read_b64_tr_b16 %0, %1" : "=v"(d) : "v"(addr));
  return d;
}

#define WAITLG(n) asm volatile("s_waitcnt lgkmcnt(" #n ")" ::: "memory")

__global__ __launch_bounds__(NTHR, 4)
void corr_mfma(const float* __restrict__ xg, const float* __restrict__ yg,
               float* __restrict__ outg) {
  __shared__ __align__(16) char smem[LDS_BYTES];

  const int bid = blockIdx.x;             // 2304 = 8 * 24 * 12
  const int b   = bid & 7;                // batch == XCD round-robin
  const int rem = bid >> 3;               // hq fastest -> h-halo L2 reuse
  const int wt  = rem / HQ;
  const int hq  = rem - wt * HQ;
  const int w0  = wt * 16;
  const int h0  = hq * 4;

  const int tid  = threadIdx.x;
  const int lane = tid & 63;
  const int wv   = tid >> 6;              // 0..7
  const int hh   = wv & 3;                // output row h0+hh
  const int dh   = wv >> 2;               // di half: di = dh*4 + dl, dl 0..4
  const int hi   = lane >> 4;
  const int lm   = lane & 15;

  const uint32_t sbase = (uint32_t)(uintptr_t)&smem[0];

  // ---- y staging decode, hoisted: 2304 quads; slots 0..3 full, slot 4 for tid<256
  uint32_t goffY[5], loffY[5];
  uint32_t vmY = 0, exY = 0;
#pragma unroll
  for (int i = 0; i < 5; ++i) {
    const int qid = i * NTHR + tid;
    goffY[i] = 0u; loffY[i] = 0u;
    if (qid < NYQ) {
      exY |= (1u << i);
      const int q = qid % 6;
      const int c = (qid / 6) & 31;
      const int r = qid / 192;            // 0..11 -> y row h0+r-4
      const int hg = h0 + r - MD;
      const int sg = w0 - MD + 4 * q;     // 4-aligned: OOB is whole-quad
      const bool ok = (hg >= 0) && (hg < H_DIM) && (sg >= 0) && (sg < W_DIM);
      if (ok) vmY |= (1u << i);
      goffY[i] = ok ? (uint32_t)(((b * C_DIM + c) * H_DIM + hg) * W_DIM + sg) : 0u;
      const int s = 4 * q;
      loffY[i] = r * YROW_B + (s >> 4) * 1024 + (c >> 2) * SUB_B + (c & 3) * 32 + (s & 15) * 2;
    }
  }

  // ---- x global-direct A-frag: lane (hi,lm) reads c = c0 + (e<4 ? hi*4+e : 16+hi*4+e-4)
  const int h = h0 + hh;
  uint32_t xoff[8];
#pragma unroll
  for (int e = 0; e < 8; ++e) {
    const int ce = (e < 4) ? (hi * 4 + e) : (16 + hi * 4 + (e - 4));
    xoff[e] = (uint32_t)(((b * C_DIM + ce) * H_DIM + h) * W_DIM + w0 + lm);
  }

  f32x4 acc[5][2];
#pragma unroll
  for (int dl = 0; dl < 5; ++dl) {
    acc[dl][0] = f32x4{0.f, 0.f, 0.f, 0.f};
    acc[dl][1] = f32x4{0.f, 0.f, 0.f, 0.f};
  }

  // B tr base: y LDS row for (hh, dh, dl) is hh + dh*4 + dl; cg = kh*4+hi -> +hi*128, kh adds 512
  const uint32_t bbase = sbase + (uint32_t)(hh + dh * 4) * YROW_B + hi * SUB_B + lm * 8;

  float4 yv[5];
  float  xv[8];
  s16x4  afr0, afr1;

  // ---- prologue: chunk 0 load+cvt+write; afr(0); issue chunk 1
  {
#pragma unroll
    for (int i = 0; i < 5; ++i) {
      float4 t4 = make_float4(0.f, 0.f, 0.f, 0.f);
      if (vmY & (1u << i)) t4 = *(const float4*)(yg + goffY[i]);
      yv[i] = t4;
    }
#pragma unroll
    for (int e = 0; e < 8; ++e) xv[e] = xg[xoff[e]];
#pragma unroll
    for (int i = 0; i < 5; ++i)
      if (exY & (1u << i))
        *(u16x4*)(smem + loffY[i]) =
            u16x4{bf16b(yv[i].x), bf16b(yv[i].y), bf16b(yv[i].z), bf16b(yv[i].w)};
    afr0[0] = (short)bf16b(xv[0]); afr0[1] = (short)bf16b(xv[1]);
    afr0[2] = (short)bf16b(xv[2]); afr0[3] = (short)bf16b(xv[3]);
    afr1[0] = (short)bf16b(xv[4]); afr1[1] = (short)bf16b(xv[5]);
    afr1[2] = (short)bf16b(xv[6]); afr1[3] = (short)bf16b(xv[7]);
    // issue chunk 1 (consumed after compute(0): covered by a full phase)
    const uint32_t co = (uint32_t)CHUNK * HWSZ;
#pragma unroll
    for (int i = 0; i < 5; ++i) {
      float4 t4 = make_float4(0.f, 0.f, 0.f, 0.f);
      if (vmY & (1u << i)) t4 = *(const float4*)(yg + goffY[i] + co);
      yv[i] = t4;
    }
#pragma unroll
    for (int e = 0; e < 8; ++e) xv[e] = xg[xoff[e] + co];
  }
  __syncthreads();

  for (int t = 0; t < NCHUNK; ++t) {
    // ---- compute chunk t from buf[t&1]: 2-slot rotated tr reads, counted waits
    const uint32_t bo = (uint32_t)(t & 1) * BUFSZ;
    s16x4 bsl[2][4];

#define ISSUE_DL(dl) { \
    const uint32_t ba = bbase + bo + (uint32_t)(dl) * YROW_B; \
    bsl[(dl) & 1][0] = tr16(ba);              /* t0 kh0 */ \
    bsl[(dl) & 1][1] = tr16(ba + 512);        /* t0 kh1 */ \
    bsl[(dl) & 1][2] = tr16(ba + 1024);       /* t1 kh0 */ \
    bsl[(dl) & 1][3] = tr16(ba + 1536); }     /* t1 kh1 */

#define DO_DL(dl, lg) \
    WAITLG(lg); __builtin_amdgcn_sched_barrier(0); \
    acc[dl][0] = __builtin_amdgcn_mfma_f32_16x16x16bf16_1k(afr0, bsl[(dl) & 1][0], acc[dl][0], 0, 0, 0); \
    acc[dl][0] = __builtin_amdgcn_mfma_f32_16x16x16bf16_1k(afr1, bsl[(dl) & 1][1], acc[dl][0], 0, 0, 0); \
    acc[dl][1] = __builtin_amdgcn_mfma_f32_16x16x16bf16_1k(afr0, bsl[(dl) & 1][2], acc[dl][1], 0, 0, 0); \
    acc[dl][1] = __builtin_amdgcn_mfma_f32_16x16x16bf16_1k(afr1, bsl[(dl) & 1][3], acc[dl][1], 0, 0, 0);

    __builtin_amdgcn_s_setprio(1);
    ISSUE_DL(0)
    ISSUE_DL(1)
    DO_DL(0, 4)
    ISSUE_DL(2)
    DO_DL(1, 4)
    ISSUE_DL(3)
    DO_DL(2, 4)
    ISSUE_DL(4)
    DO_DL(3, 4)
    DO_DL(4, 0)
    __builtin_amdgcn_s_setprio(0);
#undef ISSUE_DL
#undef DO_DL

    // ---- chunk t+1 (in flight since iter t-1): cvt + write + afr; then issue t+2
    if (t + 1 < NCHUNK) {
      const uint32_t wo = (uint32_t)((t + 1) & 1) * BUFSZ;
#pragma unroll
      for (int i = 0; i < 5; ++i)
        if (exY & (1u << i))
          *(u16x4*)(smem + wo + loffY[i]) =
              u16x4{bf16b(yv[i].x), bf16b(yv[i].y), bf16b(yv[i].z), bf16b(yv[i].w)};
      afr0[0] = (short)bf16b(xv[0]); afr0[1] = (short)bf16b(xv[1]);
      afr0[2] = (short)bf16b(xv[2]); afr0[3] = (short)bf16b(xv[3]);
      afr1[0] = (short)bf16b(xv[4]); afr1[1] = (short)bf16b(xv[5]);
      afr1[2] = (short)bf16b(xv[6]); afr1[3] = (short)bf16b(xv[7]);
      if (t + 2 < NCHUNK) {
        const uint32_t co = (uint32_t)(t + 2) * CHUNK * HWSZ;
#pragma unroll
        for (int i = 0; i < 5; ++i) {
          float4 t4 = make_float4(0.f, 0.f, 0.f, 0.f);
          if (vmY & (1u << i)) t4 = *(const float4*)(yg + goffY[i] + co);
          yv[i] = t4;
        }
#pragma unroll
        for (int e = 0; e < 8; ++e) xv[e] = xg[xoff[e] + co];
      }
    }
    // single barrier per iteration: this chunk's tr reads drained by WAITLG(0);
    // writes above target buf[(t+1)&1], last read in compute(t-1) which every
    // wave finished before the previous barrier.
    __syncthreads();
  }

  // ---- epilogue: D[m][n]: n=lm, m=hi*4+rg. dj = tt*16 + lm - m. di = dh*4+dl.
  // di=4 written by both dh-halves with bitwise-identical values (benign).
  const float scale = 1.f / 256.f;
#pragma unroll
  for (int dl = 0; dl < 5; ++dl) {
    const int di = dh * 4 + dl;
#pragma unroll
    for (int tt = 0; tt < 2; ++tt) {
#pragma unroll
      for (int rg = 0; rg < 4; ++rg) {
        const int m = hi * 4 + rg;
        const int dj = tt * 16 + lm - m;
        if (0 <= dj && dj <= 8) {
          outg[((b * (KD * KD) + di * KD + dj) * H_DIM + h) * W_DIM + w0 + m] =
              acc[dl][tt][rg] * scale;
        }
      }
    }
  }
}

extern "C" void kernel_launch(void* const* d_in, const int* in_sizes, int n_in,
                              void* d_out, int out_size, void* d_ws, size_t ws_size,
                              hipStream_t stream) {
  const float* x = (const float*)d_in[0];
  const float* y = (const float*)d_in[1];
  float* out = (float*)d_out;
  (void)in_sizes; (void)n_in; (void)d_ws; (void)ws_size; (void)out_size;

  const int grid = 8 * HQ * WTILES;       // 2304 blocks, 512 threads
  corr_mfma<<<dim3(grid), dim3(NTHR), 0, stream>>>(x, y, out);
}